// Round 6
// baseline (252.637 us; speedup 1.0000x reference)
//
#include <hip/hip_runtime.h>
#include <math.h>

// NetVLAD clustering layer, f32, MI355X — 2 kernels.
// x:[16,256,1500], centroids:[64,256], lin_w:[66,256], lin_b:[66]
// out: [16, 64*256] f32
//
// KA (chunk,u) 512 thr, 1 block/CU, TCH=96:
//   lane = t-pair (float2 math), wave = 16-f slice, K staged in 2 halves.
//   Logits flushed per (K-half, c-half-of-33) via ds_add_f32 atomics into a
//   zeroed Buf -> live acc is only 66 VGPR (round-5 spill fixed).
//   W broadcast ds_read_b128 count: 528/wave per 96 t (half of round 2).
//   All-wave redundant 3-pass softmax; agg 8c x 4f per thread over t-pairs.
// KBC (u) 1024 thr: reduce 16 chunk-partials, subtract asum*centroid,
//   intra-norm (shuffle-only), global norm via LDS rowsq, write out directly.

#define NU 16
#define NF 256
#define NT 1500
#define NC 64
#define NCG 66          // clusters + ghosts
#define EPSN 1e-12f
#define TCH 96          // 16 chunks cover 1536 >= 1500
#define NCHUNK 16

typedef float v2f __attribute__((ext_vector_type(2)));

// LDS floats: Xsm[256][98] @0 (25088) | Wsm[66][132] @25088 (8712)
//             Buf[66][96] @33800 (6336; Asm[64][98]=6272 overlays after)
// total 40136 f = 160,544 B <= 160 KiB -> 1 block/CU (8 waves).
#define XSTR 98
#define S_WSM 25088
#define S_BUF 33800
#define S_TOT 40136

// Xsm float index with within-32 XOR bank swizzle (s<32, even: keeps b64
// pairs adjacent and never crosses a 32-col block, so col stays < 96).
__device__ __forceinline__ int XS(int f, int k) {
    return f * XSTR + (k ^ (((f >> 1) & 15) << 1));
}

// ---------------- KA ----------------
__global__ __launch_bounds__(512, 2) void ka_fused(
        const float* __restrict__ x, const float* __restrict__ lin_w,
        const float* __restrict__ lin_b, float* __restrict__ partial,
        float* __restrict__ asum_part) {
    __shared__ float S[S_TOT];
    float* Wsm = S + S_WSM;
    float* Buf = S + S_BUF;

    const int chunk = blockIdx.x, u = blockIdx.y;
    const int tid = threadIdx.x, lane = tid & 63, wave = tid >> 6;
    const int t0 = chunk * TCH;

    // ---- stage X (swizzled) + zero Buf + stage W K-half 0 ----
    {
        const int fr = tid >> 3;          // 0..63
        const int ks = (tid & 7) * 4;     // 0,4,...,28
        #pragma unroll
        for (int r = 0; r < 4; ++r) {
            const int f = fr + 64 * r;
            const float* rp = x + (size_t)(u * NF + f) * NT + t0;
            #pragma unroll
            for (int q = 0; q < 3; ++q) {
                const int kk = ks + 32 * q;        // 0..92
                const int tg = t0 + kk;
                float4 v;
                if (tg + 3 < NT) v = *(const float4*)(rp + kk);  // 16B-aligned
                else {
                    v.x = (tg + 0 < NT) ? rp[kk + 0] : 0.0f;
                    v.y = (tg + 1 < NT) ? rp[kk + 1] : 0.0f;
                    v.z = (tg + 2 < NT) ? rp[kk + 2] : 0.0f;
                    v.w = (tg + 3 < NT) ? rp[kk + 3] : 0.0f;
                }
                *(v2f*)&S[XS(f, kk)]     = (v2f){v.x, v.y};
                *(v2f*)&S[XS(f, kk + 2)] = (v2f){v.z, v.w};
            }
        }
        for (int i = tid; i < NCG * 96; i += 512) Buf[i] = 0.0f;
        for (int i = tid; i < NCG * 128; i += 512) {
            const int c = i >> 7, k = i & 127;
            Wsm[c * 132 + k] = lin_w[c * NF + k];
        }
    }
    __syncthreads();

    const int lp = (lane < 48) ? lane : 47;   // lanes 48-63 duplicate pair 47

    // ---- logits: K in 2 staged halves, c in 2 halves of 33 (acc = 66 VGPR) ----
    #pragma unroll
    for (int kh = 0; kh < 2; ++kh) {
        v2f xv[16];
        const int fb = kh * 128 + wave * 16;       // this wave's 16-f slice
        #pragma unroll
        for (int k2 = 0; k2 < 16; ++k2)
            xv[k2] = *(const v2f*)&S[XS(fb + k2, 2 * lp)];

        #pragma unroll
        for (int ch = 0; ch < 2; ++ch) {
            v2f acc[33];
            #pragma unroll
            for (int c = 0; c < 33; ++c) acc[c] = (v2f){0.0f, 0.0f};
            #pragma unroll
            for (int c = 0; c < 33; ++c) {
                const float4* wp =
                    (const float4*)&Wsm[(ch * 33 + c) * 132 + wave * 16];
                const float4 w0 = wp[0], w1 = wp[1], w2 = wp[2], w3 = wp[3];
                v2f a = acc[c];
                a += xv[0]  * w0.x; a += xv[1]  * w0.y; a += xv[2]  * w0.z; a += xv[3]  * w0.w;
                a += xv[4]  * w1.x; a += xv[5]  * w1.y; a += xv[6]  * w1.z; a += xv[7]  * w1.w;
                a += xv[8]  * w2.x; a += xv[9]  * w2.y; a += xv[10] * w2.z; a += xv[11] * w2.w;
                a += xv[12] * w3.x; a += xv[13] * w3.y; a += xv[14] * w3.z; a += xv[15] * w3.w;
                acc[c] = a;
            }
            if (lane < 48) {
                #pragma unroll
                for (int c = 0; c < 33; ++c) {
                    atomicAdd(&Buf[(ch * 33 + c) * 96 + 2 * lp],     acc[c].x);
                    atomicAdd(&Buf[(ch * 33 + c) * 96 + 2 * lp + 1], acc[c].y);
                }
            }
        }
        __syncthreads();                  // kh=0: Wsm reads done; kh=1: atomics done
        if (kh == 0) {
            for (int i = tid; i < NCG * 128; i += 512) {
                const int c = i >> 7, k = i & 127;
                Wsm[c * 132 + k] = lin_w[c * NF + 128 + k];
            }
            __syncthreads();
        }
    }

    // ---- all-wave redundant softmax over this lane's t-pair (3-pass) ----
    v2f mx = (v2f){-INFINITY, -INFINITY};
    #pragma unroll
    for (int c = 0; c < NCG; ++c) {
        const v2f l = *(const v2f*)&Buf[c * 96 + 2 * lp];
        const float b = lin_b[c];
        mx.x = fmaxf(mx.x, l.x + b); mx.y = fmaxf(mx.y, l.y + b);
    }
    v2f sm = (v2f){0.0f, 0.0f};
    #pragma unroll
    for (int c = 0; c < NCG; ++c) {
        const v2f l = *(const v2f*)&Buf[c * 96 + 2 * lp];
        const float b = lin_b[c];
        sm.x += __expf(l.x + b - mx.x);
        sm.y += __expf(l.y + b - mx.y);
    }
    const int tA = t0 + 2 * lp;
    const float sA = (tA     < NT) ? (1.0f / sm.x) : 0.0f;   // zero padded t's
    const float sB = (tA + 1 < NT) ? (1.0f / sm.y) : 0.0f;
    // this wave's 8-c Asm slice: read + exp + scale BEFORE the overlay barrier
    v2f aout[8];
    #pragma unroll
    for (int i = 0; i < 8; ++i) {
        const int c = wave * 8 + i;
        const v2f l = *(const v2f*)&Buf[c * 96 + 2 * lp];
        const float b = lin_b[c];
        aout[i] = (v2f){__expf(l.x + b - mx.x) * sA,
                        __expf(l.y + b - mx.y) * sB};
    }
    __syncthreads();                       // all Buf reads complete
    if (lane < 48) {
        #pragma unroll
        for (int i = 0; i < 8; ++i)        // Asm[c][t] overlays Buf, stride 98
            *(v2f*)&Buf[(wave * 8 + i) * XSTR + 2 * lp] = aout[i];
    }
    __syncthreads();

    // ---- aggregation: wave -> 8 c's, lane -> 4 f's (f = lane+64j), t-pairs ----
    {
        const int cb = wave * 8;
        v2f ag[8][4], as[8];
        #pragma unroll
        for (int i = 0; i < 8; ++i) {
            as[i] = (v2f){0.0f, 0.0f};
            #pragma unroll
            for (int j = 0; j < 4; ++j) ag[i][j] = (v2f){0.0f, 0.0f};
        }
        for (int kp = 0; kp < TCH / 2; ++kp) {
            v2f av[8], xv2[4];
            #pragma unroll
            for (int i = 0; i < 8; ++i)      // wave-uniform -> broadcast, no conflict
                av[i] = *(const v2f*)&Buf[(cb + i) * XSTR + 2 * kp];
            #pragma unroll
            for (int j = 0; j < 4; ++j)      // swizzle -> 2-way (free)
                xv2[j] = *(const v2f*)&S[XS(lane + 64 * j, 2 * kp)];
            #pragma unroll
            for (int i = 0; i < 8; ++i) {
                as[i] += av[i];
                #pragma unroll
                for (int j = 0; j < 4; ++j) ag[i][j] += av[i] * xv2[j];
            }
        }
        #pragma unroll
        for (int i = 0; i < 8; ++i) {
            float* op = partial + ((size_t)((chunk * NU + u) * NC + cb + i)) * NF;
            #pragma unroll
            for (int j = 0; j < 4; ++j) op[lane + 64 * j] = ag[i][j].x + ag[i][j].y;
        }
        if (lane == 0) {
            #pragma unroll
            for (int i = 0; i < 8; ++i)
                asum_part[(chunk * NU + u) * NC + cb + i] = as[i].x + as[i].y;
        }
    }
}

// ---------------- KBC: reduce + intra-norm + global norm ----------------
__global__ __launch_bounds__(1024) void kbc(
        const float* __restrict__ asum_part, const float* __restrict__ partial,
        const float* __restrict__ centroids, float* __restrict__ out) {
    const int u = blockIdx.x;
    const int tid = threadIdx.x, lane = tid & 63, wave = tid >> 6;  // 16 waves
    __shared__ float rq[NC];

    float4 keep[4];
    float dinv[4];
    #pragma unroll
    for (int i = 0; i < 4; ++i) {
        const int c = wave + 16 * i;                 // wave-uniform
        float asum = 0.0f;                           // -> scalar loads
        #pragma unroll
        for (int ch = 0; ch < NCHUNK; ++ch)
            asum += asum_part[(ch * NU + u) * NC + c];

        float4 val = make_float4(0.f, 0.f, 0.f, 0.f);
        #pragma unroll
        for (int ch = 0; ch < NCHUNK; ++ch) {
            const float4 p = *(const float4*)(
                partial + ((size_t)((ch * NU + u) * NC + c)) * NF + lane * 4);
            val.x += p.x; val.y += p.y; val.z += p.z; val.w += p.w;
        }
        const float4 ce = *(const float4*)(centroids + c * NF + lane * 4);
        val.x -= asum * ce.x; val.y -= asum * ce.y;
        val.z -= asum * ce.z; val.w -= asum * ce.w;

        float ss = val.x * val.x + val.y * val.y + val.z * val.z + val.w * val.w;
        #pragma unroll
        for (int off = 32; off > 0; off >>= 1) ss += __shfl_down(ss, off, 64);
        ss = __shfl(ss, 0, 64);

        const float d = fmaxf(sqrtf(ss), EPSN);
        keep[i] = val;
        dinv[i] = 1.0f / d;
        if (lane == 0) rq[c] = ss / (d * d);
    }
    __syncthreads();
    float g = 0.0f;
    #pragma unroll
    for (int c = 0; c < NC; ++c) g += rq[c];         // uniform broadcast reads
    const float ginv = 1.0f / fmaxf(sqrtf(g), EPSN);
    #pragma unroll
    for (int i = 0; i < 4; ++i) {
        const int c = wave + 16 * i;
        const float sc = dinv[i] * ginv;
        float4 o = keep[i];
        o.x *= sc; o.y *= sc; o.z *= sc; o.w *= sc;
        *(float4*)(out + (size_t)u * (NC * NF) + c * NF + lane * 4) = o;
    }
}

// ---------------- launcher ----------------
extern "C" void kernel_launch(void* const* d_in, const int* in_sizes, int n_in,
                              void* d_out, int out_size, void* d_ws, size_t ws_size,
                              hipStream_t stream) {
    (void)in_sizes; (void)n_in; (void)out_size; (void)ws_size;
    const float* x         = (const float*)d_in[0];
    const float* centroids = (const float*)d_in[1];
    const float* lin_w     = (const float*)d_in[2];
    const float* lin_b     = (const float*)d_in[3];
    float* out = (float*)d_out;

    float* ws        = (float*)d_ws;
    float* partial   = ws;                                      // 16*16*64*256 f
    float* asum_part = partial + (size_t)NCHUNK * NU * NC * NF; // 16*16*64 f (~16.8 MB)

    hipLaunchKernelGGL(ka_fused, dim3(NCHUNK, NU), dim3(512), 0, stream,
                       x, lin_w, lin_b, partial, asum_part);
    hipLaunchKernelGGL(kbc, dim3(NU), dim3(1024), 0, stream,
                       asum_part, partial, centroids, out);
}

// Round 7
// 124.390 us; speedup vs baseline: 2.0310x; 2.0310x over previous
//
#include <hip/hip_runtime.h>
#include <math.h>

// NetVLAD clustering layer, f32, MI355X — 2 kernels.
// x:[16,256,1500], centroids:[64,256], lin_w:[66,256], lin_b:[66]
// out: [16, 64*256] f32
//
// KA (chunk,u) 512 thr, 1 block/CU, TCH=96, OUTPUT-PARTITIONED logits:
//   wave owns 8-9 clusters and contracts ALL 256 f for them -> exactly ONE
//   W broadcast sweep per chunk (half of round-2's replicated sweeps) and
//   ZERO cross-wave reduction (no tree, no atomics, 6 barriers total).
//   Lane owns a t-pair (48 lanes active in logits), acc = 9 v2f = 18 VGPR.
//   W staged in two 128-f halves; raw logits -> Buf; all-wave redundant
//   softmax (each wave rescales its own c-rows from live acc); agg 8c x 4f
//   per thread over t-pairs with folded asum.
// KBC (u) 1024 thr: reduce 16 chunk-partials, subtract asum*centroid,
//   intra-norm (shuffle-only), global norm via LDS rowsq, write out.

#define NU 16
#define NF 256
#define NT 1500
#define NC 64
#define NCG 66          // clusters + ghosts
#define EPSN 1e-12f
#define TCH 96          // 16 chunks cover 1536 >= 1500
#define NCHUNK 16

typedef float v2f __attribute__((ext_vector_type(2)));

// LDS floats: Xsm[256][96] @0 (24576) | Wsm[66][132] @24576 (8712)
//             Buf[66][96]  @33288 (6336)   total 39624 f = 158,496 B
#define S_WSM 24576
#define S_BUF 33288
#define S_TOT 39624

// Xsm index, pair-granular XOR swizzle within 32-col blocks.
// Rows are stride 96 (96%32==0), so without swizzle all rows share banks;
// XOR bits 1..4 with (f&15)<<1 keeps pairs intact, col stays < 96, and
// spreads 16 rows across 16 distinct pair-slots (2-way residual = free).
__device__ __forceinline__ int XS(int f, int k) {
    return f * 96 + (k ^ ((f & 15) << 1));
}

// ---------------- KA ----------------
__global__ __launch_bounds__(512, 2) void ka_fused(
        const float* __restrict__ x, const float* __restrict__ lin_w,
        const float* __restrict__ lin_b, float* __restrict__ partial,
        float* __restrict__ asum_part) {
    __shared__ float S[S_TOT];
    float* Wsm = S + S_WSM;
    float* Buf = S + S_BUF;

    const int chunk = blockIdx.x, u = blockIdx.y;
    const int tid = threadIdx.x, lane = tid & 63, wave = tid >> 6;
    const int t0 = chunk * TCH;

    // ---- stage X (swizzled, zero-fill past NT) + W f-half 0 ----
    {
        const int fr = tid >> 3;           // 0..63
        const int ks = (tid & 7) * 4;      // 0,4,...,28
        #pragma unroll
        for (int r = 0; r < 4; ++r) {
            const int f = fr + 64 * r;
            const float* rp = x + (size_t)(u * NF + f) * NT + t0;
            #pragma unroll
            for (int q = 0; q < 3; ++q) {
                const int kk = ks + 32 * q;        // 0..92
                const int tg = t0 + kk;
                float4 v;
                if (tg + 3 < NT) v = *(const float4*)(rp + kk);  // 16B-aligned
                else {
                    v.x = (tg + 0 < NT) ? rp[kk + 0] : 0.0f;
                    v.y = (tg + 1 < NT) ? rp[kk + 1] : 0.0f;
                    v.z = (tg + 2 < NT) ? rp[kk + 2] : 0.0f;
                    v.w = (tg + 3 < NT) ? rp[kk + 3] : 0.0f;
                }
                *(v2f*)&S[XS(f, kk)]     = (v2f){v.x, v.y};
                *(v2f*)&S[XS(f, kk + 2)] = (v2f){v.z, v.w};
            }
        }
        for (int i = tid; i < NCG * 128; i += 512) {
            const int c = i >> 7, k = i & 127;
            Wsm[c * 132 + k] = lin_w[c * NF + k];
        }
    }
    __syncthreads();                                           // B1

    // wave -> cluster slice: waves 0,1 take 9 c's; waves 2..7 take 8 c's.
    const int nmy = (wave < 2) ? 9 : 8;
    const int c0  = (wave < 2) ? wave * 9 : 18 + (wave - 2) * 8;
    const int lp  = (lane < 48) ? lane : 47;   // t-pair index; 48-63 duplicate

    v2f acc[9];
    #pragma unroll
    for (int i = 0; i < 9; ++i) acc[i] = (v2f){0.0f, 0.0f};

    // ---- logits: contract all 256 f for this wave's clusters ----
    #pragma unroll
    for (int kh = 0; kh < 2; ++kh) {
        #pragma unroll
        for (int fc = 0; fc < 8; ++fc) {
            const int fb = fc * 16;                 // within current W half
            v2f xv[16];
            #pragma unroll
            for (int k2 = 0; k2 < 16; ++k2)
                xv[k2] = *(const v2f*)&S[XS(kh * 128 + fb + k2, 2 * lp)];
            #pragma unroll
            for (int i = 0; i < 9; ++i) {
                if (i < nmy) {                      // wave-uniform guard
                    const float4* wp = (const float4*)&Wsm[(c0 + i) * 132 + fb];
                    const float4 w0 = wp[0], w1 = wp[1], w2 = wp[2], w3 = wp[3];
                    v2f a = acc[i];
                    a += xv[0]  * w0.x; a += xv[1]  * w0.y; a += xv[2]  * w0.z; a += xv[3]  * w0.w;
                    a += xv[4]  * w1.x; a += xv[5]  * w1.y; a += xv[6]  * w1.z; a += xv[7]  * w1.w;
                    a += xv[8]  * w2.x; a += xv[9]  * w2.y; a += xv[10] * w2.z; a += xv[11] * w2.w;
                    a += xv[12] * w3.x; a += xv[13] * w3.y; a += xv[14] * w3.z; a += xv[15] * w3.w;
                    acc[i] = a;
                }
            }
        }
        __syncthreads();                                       // B2 / B4a
        if (kh == 0) {
            for (int i = tid; i < NCG * 128; i += 512) {       // stage half 1
                const int c = i >> 7, k = i & 127;
                Wsm[c * 132 + k] = lin_w[c * NF + 128 + k];
            }
            __syncthreads();                                   // B3
        }
    }

    // ---- publish raw logits ----
    if (lane < 48) {
        #pragma unroll
        for (int i = 0; i < 9; ++i)
            if (i < nmy)
                *(v2f*)&Buf[(c0 + i) * 96 + 2 * lp] = acc[i];
    }
    __syncthreads();                                           // B4

    // ---- all-wave redundant softmax for this lane's t-pair (2-pass) ----
    v2f mx = (v2f){-INFINITY, -INFINITY};
    #pragma unroll
    for (int c = 0; c < NCG; ++c) {
        const v2f l = *(const v2f*)&Buf[c * 96 + 2 * lp];
        const float b = lin_b[c];
        mx.x = fmaxf(mx.x, l.x + b); mx.y = fmaxf(mx.y, l.y + b);
    }
    v2f sm = (v2f){0.0f, 0.0f};
    #pragma unroll
    for (int c = 0; c < NCG; ++c) {
        const v2f l = *(const v2f*)&Buf[c * 96 + 2 * lp];
        const float b = lin_b[c];
        sm.x += __expf(l.x + b - mx.x);
        sm.y += __expf(l.y + b - mx.y);
    }
    const int tA = t0 + 2 * lp;
    const float sA = (tA     < NT) ? (1.0f / sm.x) : 0.0f;     // zero padded t's
    const float sB = (tA + 1 < NT) ? (1.0f / sm.y) : 0.0f;
    // this wave's softmaxed rows from LIVE acc (no re-read)
    v2f aout[9];
    #pragma unroll
    for (int i = 0; i < 9; ++i) {
        const float b = lin_b[c0 + ((i < nmy) ? i : 0)];
        aout[i] = (v2f){__expf(acc[i].x + b - mx.x) * sA,
                        __expf(acc[i].y + b - mx.y) * sB};
    }
    __syncthreads();                                           // B5: Buf reads done
    if (lane < 48) {
        #pragma unroll
        for (int i = 0; i < 9; ++i)
            if (i < nmy)
                *(v2f*)&Buf[(c0 + i) * 96 + 2 * lp] = aout[i]; // overlay: a[c][t]
    }
    __syncthreads();                                           // B6

    // ---- aggregation: wave -> 8 c's, lane -> 4 f's (f = lane+64j), t-pairs ----
    {
        const int cb = wave * 8;
        v2f ag[8][4], as[8];
        #pragma unroll
        for (int i = 0; i < 8; ++i) {
            as[i] = (v2f){0.0f, 0.0f};
            #pragma unroll
            for (int j = 0; j < 4; ++j) ag[i][j] = (v2f){0.0f, 0.0f};
        }
        for (int kp = 0; kp < TCH / 2; ++kp) {
            v2f av[8], xv2[4];
            #pragma unroll
            for (int i = 0; i < 8; ++i)      // wave-uniform addr -> broadcast
                av[i] = *(const v2f*)&Buf[(cb + i) * 96 + 2 * kp];
            #pragma unroll
            for (int j = 0; j < 4; ++j)
                xv2[j] = *(const v2f*)&S[XS(lane + 64 * j, 2 * kp)];
            #pragma unroll
            for (int i = 0; i < 8; ++i) {
                as[i] += av[i];
                #pragma unroll
                for (int j = 0; j < 4; ++j) ag[i][j] += av[i] * xv2[j];
            }
        }
        #pragma unroll
        for (int i = 0; i < 8; ++i) {
            float* op = partial + ((size_t)((chunk * NU + u) * NC + cb + i)) * NF;
            #pragma unroll
            for (int j = 0; j < 4; ++j) op[lane + 64 * j] = ag[i][j].x + ag[i][j].y;
        }
        if (lane == 0) {
            #pragma unroll
            for (int i = 0; i < 8; ++i)
                asum_part[(chunk * NU + u) * NC + cb + i] = as[i].x + as[i].y;
        }
    }
}

// ---------------- KBC: reduce + intra-norm + global norm ----------------
__global__ __launch_bounds__(1024) void kbc(
        const float* __restrict__ asum_part, const float* __restrict__ partial,
        const float* __restrict__ centroids, float* __restrict__ out) {
    const int u = blockIdx.x;
    const int tid = threadIdx.x, lane = tid & 63, wave = tid >> 6;  // 16 waves
    __shared__ float rq[NC];

    float4 keep[4];
    float dinv[4];
    #pragma unroll
    for (int i = 0; i < 4; ++i) {
        const int c = wave + 16 * i;                 // wave-uniform
        float asum = 0.0f;                           // -> scalar loads
        #pragma unroll
        for (int ch = 0; ch < NCHUNK; ++ch)
            asum += asum_part[(ch * NU + u) * NC + c];

        float4 val = make_float4(0.f, 0.f, 0.f, 0.f);
        #pragma unroll
        for (int ch = 0; ch < NCHUNK; ++ch) {
            const float4 p = *(const float4*)(
                partial + ((size_t)((ch * NU + u) * NC + c)) * NF + lane * 4);
            val.x += p.x; val.y += p.y; val.z += p.z; val.w += p.w;
        }
        const float4 ce = *(const float4*)(centroids + c * NF + lane * 4);
        val.x -= asum * ce.x; val.y -= asum * ce.y;
        val.z -= asum * ce.z; val.w -= asum * ce.w;

        float ss = val.x * val.x + val.y * val.y + val.z * val.z + val.w * val.w;
        #pragma unroll
        for (int off = 32; off > 0; off >>= 1) ss += __shfl_down(ss, off, 64);
        ss = __shfl(ss, 0, 64);

        const float d = fmaxf(sqrtf(ss), EPSN);
        keep[i] = val;
        dinv[i] = 1.0f / d;
        if (lane == 0) rq[c] = ss / (d * d);
    }
    __syncthreads();
    float g = 0.0f;
    #pragma unroll
    for (int c = 0; c < NC; ++c) g += rq[c];         // uniform broadcast reads
    const float ginv = 1.0f / fmaxf(sqrtf(g), EPSN);
    #pragma unroll
    for (int i = 0; i < 4; ++i) {
        const int c = wave + 16 * i;
        const float sc = dinv[i] * ginv;
        float4 o = keep[i];
        o.x *= sc; o.y *= sc; o.z *= sc; o.w *= sc;
        *(float4*)(out + (size_t)u * (NC * NF) + c * NF + lane * 4) = o;
    }
}

// ---------------- launcher ----------------
extern "C" void kernel_launch(void* const* d_in, const int* in_sizes, int n_in,
                              void* d_out, int out_size, void* d_ws, size_t ws_size,
                              hipStream_t stream) {
    (void)in_sizes; (void)n_in; (void)out_size; (void)ws_size;
    const float* x         = (const float*)d_in[0];
    const float* centroids = (const float*)d_in[1];
    const float* lin_w     = (const float*)d_in[2];
    const float* lin_b     = (const float*)d_in[3];
    float* out = (float*)d_out;

    float* ws        = (float*)d_ws;
    float* partial   = ws;                                      // 16*16*64*256 f
    float* asum_part = partial + (size_t)NCHUNK * NU * NC * NF; // 16*16*64 f (~16.8 MB)

    hipLaunchKernelGGL(ka_fused, dim3(NCHUNK, NU), dim3(512), 0, stream,
                       x, lin_w, lin_b, partial, asum_part);
    hipLaunchKernelGGL(kbc, dim3(NU), dim3(1024), 0, stream,
                       asum_part, partial, centroids, out);
}

// Round 8
// 113.715 us; speedup vs baseline: 2.2217x; 1.0939x over previous
//
#include <hip/hip_runtime.h>
#include <math.h>

// NetVLAD clustering layer, f32, MI355X — 2 kernels.
// x:[16,256,1500], centroids:[64,256], lin_w:[66,256], lin_b:[66]
// out: [16, 64*256] f32
//
// KA (chunk,u) 512 thr, 1 block/CU, TCH=96, OUTPUT-PARTITIONED logits
//   (unchanged from round 7, measured ~50 us): wave owns 8-9 clusters and
//   contracts all 256 f -> ONE W broadcast sweep per chunk, zero cross-wave
//   reduction. Lane owns a t-pair; all-wave redundant softmax; agg 8c x 4f.
// KB2 (cgroup,u) 256 blocks, wave-per-c: reduce 16 chunk-partials, subtract
//   asum*centroid, intra-normalize, apply global scale. KEY: each
//   intra-normalized row has unit L2 norm (rowsq = ss/d^2 == 1 for any
//   non-degenerate row), so the global norm is exactly 1/sqrt(64) = 0.125 —
//   no cross-block rowsq reduction needed. This replaces round-7's 16-block
//   KBC (~30-45 us, 6% machine utilization) with a 256-block kernel (~5 us).

#define NU 16
#define NF 256
#define NT 1500
#define NC 64
#define NCG 66          // clusters + ghosts
#define EPSN 1e-12f
#define TCH 96          // 16 chunks cover 1536 >= 1500
#define NCHUNK 16
#define GINV 0.125f     // 1/sqrt(NC): global L2 norm of NC unit-norm rows

typedef float v2f __attribute__((ext_vector_type(2)));

// LDS floats: Xsm[256][96] @0 (24576) | Wsm[66][132] @24576 (8712)
//             Buf[66][96]  @33288 (6336)   total 39624 f = 158,496 B
#define S_WSM 24576
#define S_BUF 33288
#define S_TOT 39624

// Xsm index, pair-granular XOR swizzle within 32-col blocks.
__device__ __forceinline__ int XS(int f, int k) {
    return f * 96 + (k ^ ((f & 15) << 1));
}

// ---------------- KA (unchanged from round 7) ----------------
__global__ __launch_bounds__(512, 2) void ka_fused(
        const float* __restrict__ x, const float* __restrict__ lin_w,
        const float* __restrict__ lin_b, float* __restrict__ partial,
        float* __restrict__ asum_part) {
    __shared__ float S[S_TOT];
    float* Wsm = S + S_WSM;
    float* Buf = S + S_BUF;

    const int chunk = blockIdx.x, u = blockIdx.y;
    const int tid = threadIdx.x, lane = tid & 63, wave = tid >> 6;
    const int t0 = chunk * TCH;

    // ---- stage X (swizzled, zero-fill past NT) + W f-half 0 ----
    {
        const int fr = tid >> 3;           // 0..63
        const int ks = (tid & 7) * 4;      // 0,4,...,28
        #pragma unroll
        for (int r = 0; r < 4; ++r) {
            const int f = fr + 64 * r;
            const float* rp = x + (size_t)(u * NF + f) * NT + t0;
            #pragma unroll
            for (int q = 0; q < 3; ++q) {
                const int kk = ks + 32 * q;        // 0..92
                const int tg = t0 + kk;
                float4 v;
                if (tg + 3 < NT) v = *(const float4*)(rp + kk);  // 16B-aligned
                else {
                    v.x = (tg + 0 < NT) ? rp[kk + 0] : 0.0f;
                    v.y = (tg + 1 < NT) ? rp[kk + 1] : 0.0f;
                    v.z = (tg + 2 < NT) ? rp[kk + 2] : 0.0f;
                    v.w = (tg + 3 < NT) ? rp[kk + 3] : 0.0f;
                }
                *(v2f*)&S[XS(f, kk)]     = (v2f){v.x, v.y};
                *(v2f*)&S[XS(f, kk + 2)] = (v2f){v.z, v.w};
            }
        }
        for (int i = tid; i < NCG * 128; i += 512) {
            const int c = i >> 7, k = i & 127;
            Wsm[c * 132 + k] = lin_w[c * NF + k];
        }
    }
    __syncthreads();                                           // B1

    // wave -> cluster slice: waves 0,1 take 9 c's; waves 2..7 take 8 c's.
    const int nmy = (wave < 2) ? 9 : 8;
    const int c0  = (wave < 2) ? wave * 9 : 18 + (wave - 2) * 8;
    const int lp  = (lane < 48) ? lane : 47;   // t-pair index; 48-63 duplicate

    v2f acc[9];
    #pragma unroll
    for (int i = 0; i < 9; ++i) acc[i] = (v2f){0.0f, 0.0f};

    // ---- logits: contract all 256 f for this wave's clusters ----
    #pragma unroll
    for (int kh = 0; kh < 2; ++kh) {
        #pragma unroll
        for (int fc = 0; fc < 8; ++fc) {
            const int fb = fc * 16;                 // within current W half
            v2f xv[16];
            #pragma unroll
            for (int k2 = 0; k2 < 16; ++k2)
                xv[k2] = *(const v2f*)&S[XS(kh * 128 + fb + k2, 2 * lp)];
            #pragma unroll
            for (int i = 0; i < 9; ++i) {
                if (i < nmy) {                      // wave-uniform guard
                    const float4* wp = (const float4*)&Wsm[(c0 + i) * 132 + fb];
                    const float4 w0 = wp[0], w1 = wp[1], w2 = wp[2], w3 = wp[3];
                    v2f a = acc[i];
                    a += xv[0]  * w0.x; a += xv[1]  * w0.y; a += xv[2]  * w0.z; a += xv[3]  * w0.w;
                    a += xv[4]  * w1.x; a += xv[5]  * w1.y; a += xv[6]  * w1.z; a += xv[7]  * w1.w;
                    a += xv[8]  * w2.x; a += xv[9]  * w2.y; a += xv[10] * w2.z; a += xv[11] * w2.w;
                    a += xv[12] * w3.x; a += xv[13] * w3.y; a += xv[14] * w3.z; a += xv[15] * w3.w;
                    acc[i] = a;
                }
            }
        }
        __syncthreads();                                       // B2 / B4a
        if (kh == 0) {
            for (int i = tid; i < NCG * 128; i += 512) {       // stage half 1
                const int c = i >> 7, k = i & 127;
                Wsm[c * 132 + k] = lin_w[c * NF + 128 + k];
            }
            __syncthreads();                                   // B3
        }
    }

    // ---- publish raw logits ----
    if (lane < 48) {
        #pragma unroll
        for (int i = 0; i < 9; ++i)
            if (i < nmy)
                *(v2f*)&Buf[(c0 + i) * 96 + 2 * lp] = acc[i];
    }
    __syncthreads();                                           // B4

    // ---- all-wave redundant softmax for this lane's t-pair (2-pass) ----
    v2f mx = (v2f){-INFINITY, -INFINITY};
    #pragma unroll
    for (int c = 0; c < NCG; ++c) {
        const v2f l = *(const v2f*)&Buf[c * 96 + 2 * lp];
        const float b = lin_b[c];
        mx.x = fmaxf(mx.x, l.x + b); mx.y = fmaxf(mx.y, l.y + b);
    }
    v2f sm = (v2f){0.0f, 0.0f};
    #pragma unroll
    for (int c = 0; c < NCG; ++c) {
        const v2f l = *(const v2f*)&Buf[c * 96 + 2 * lp];
        const float b = lin_b[c];
        sm.x += __expf(l.x + b - mx.x);
        sm.y += __expf(l.y + b - mx.y);
    }
    const int tA = t0 + 2 * lp;
    const float sA = (tA     < NT) ? (1.0f / sm.x) : 0.0f;     // zero padded t's
    const float sB = (tA + 1 < NT) ? (1.0f / sm.y) : 0.0f;
    // this wave's softmaxed rows from LIVE acc (no re-read)
    v2f aout[9];
    #pragma unroll
    for (int i = 0; i < 9; ++i) {
        const float b = lin_b[c0 + ((i < nmy) ? i : 0)];
        aout[i] = (v2f){__expf(acc[i].x + b - mx.x) * sA,
                        __expf(acc[i].y + b - mx.y) * sB};
    }
    __syncthreads();                                           // B5: Buf reads done
    if (lane < 48) {
        #pragma unroll
        for (int i = 0; i < 9; ++i)
            if (i < nmy)
                *(v2f*)&Buf[(c0 + i) * 96 + 2 * lp] = aout[i]; // overlay: a[c][t]
    }
    __syncthreads();                                           // B6

    // ---- aggregation: wave -> 8 c's, lane -> 4 f's (f = lane+64j), t-pairs ----
    {
        const int cb = wave * 8;
        v2f ag[8][4], as[8];
        #pragma unroll
        for (int i = 0; i < 8; ++i) {
            as[i] = (v2f){0.0f, 0.0f};
            #pragma unroll
            for (int j = 0; j < 4; ++j) ag[i][j] = (v2f){0.0f, 0.0f};
        }
        for (int kp = 0; kp < TCH / 2; ++kp) {
            v2f av[8], xv2[4];
            #pragma unroll
            for (int i = 0; i < 8; ++i)      // wave-uniform addr -> broadcast
                av[i] = *(const v2f*)&Buf[(cb + i) * 96 + 2 * kp];
            #pragma unroll
            for (int j = 0; j < 4; ++j)
                xv2[j] = *(const v2f*)&S[XS(lane + 64 * j, 2 * kp)];
            #pragma unroll
            for (int i = 0; i < 8; ++i) {
                as[i] += av[i];
                #pragma unroll
                for (int j = 0; j < 4; ++j) ag[i][j] += av[i] * xv2[j];
            }
        }
        #pragma unroll
        for (int i = 0; i < 8; ++i) {
            float* op = partial + ((size_t)((chunk * NU + u) * NC + cb + i)) * NF;
            #pragma unroll
            for (int j = 0; j < 4; ++j) op[lane + 64 * j] = ag[i][j].x + ag[i][j].y;
        }
        if (lane == 0) {
            #pragma unroll
            for (int i = 0; i < 8; ++i)
                asum_part[(chunk * NU + u) * NC + cb + i] = as[i].x + as[i].y;
        }
    }
}

// ---------------- KB2: reduce + intra-norm + constant global norm ----------
// grid (16, 16) = 256 blocks (1/CU), 256 thr, wave-per-c.
__global__ __launch_bounds__(256) void kb2(
        const float* __restrict__ asum_part, const float* __restrict__ partial,
        const float* __restrict__ centroids, float* __restrict__ out) {
    const int u = blockIdx.y;
    const int wave = threadIdx.x >> 6, lane = threadIdx.x & 63;
    const int c = blockIdx.x * 4 + wave;         // 0..63

    float asum = 0.0f;                           // wave-uniform -> scalar loads
    #pragma unroll
    for (int ch = 0; ch < NCHUNK; ++ch)
        asum += asum_part[(ch * NU + u) * NC + c];

    float4 val = make_float4(0.f, 0.f, 0.f, 0.f);
    #pragma unroll
    for (int ch = 0; ch < NCHUNK; ++ch) {
        const float4 p = *(const float4*)(
            partial + ((size_t)((ch * NU + u) * NC + c)) * NF + lane * 4);
        val.x += p.x; val.y += p.y; val.z += p.z; val.w += p.w;
    }
    const float4 ce = *(const float4*)(centroids + c * NF + lane * 4);
    val.x -= asum * ce.x; val.y -= asum * ce.y;
    val.z -= asum * ce.z; val.w -= asum * ce.w;

    float ss = val.x * val.x + val.y * val.y + val.z * val.z + val.w * val.w;
    #pragma unroll
    for (int off = 32; off > 0; off >>= 1) ss += __shfl_down(ss, off, 64);
    ss = __shfl(ss, 0, 64);                      // broadcast row sum-sq

    // intra-norm 1/d, then global norm: each normalized row has ||.||=1,
    // so ||sv|| = sqrt(NC) exactly -> constant GINV (degenerate all-zero
    // rows output 0 either way).
    const float sc = GINV / fmaxf(sqrtf(ss), EPSN);
    float4 o;
    o.x = val.x * sc; o.y = val.y * sc; o.z = val.z * sc; o.w = val.w * sc;
    *(float4*)(out + (size_t)u * (NC * NF) + c * NF + lane * 4) = o;
}

// ---------------- launcher ----------------
extern "C" void kernel_launch(void* const* d_in, const int* in_sizes, int n_in,
                              void* d_out, int out_size, void* d_ws, size_t ws_size,
                              hipStream_t stream) {
    (void)in_sizes; (void)n_in; (void)out_size; (void)ws_size;
    const float* x         = (const float*)d_in[0];
    const float* centroids = (const float*)d_in[1];
    const float* lin_w     = (const float*)d_in[2];
    const float* lin_b     = (const float*)d_in[3];
    float* out = (float*)d_out;

    float* ws        = (float*)d_ws;
    float* partial   = ws;                                      // 16*16*64*256 f
    float* asum_part = partial + (size_t)NCHUNK * NU * NC * NF; // 16*16*64 f (~16.8 MB)

    hipLaunchKernelGGL(ka_fused, dim3(NCHUNK, NU), dim3(512), 0, stream,
                       x, lin_w, lin_b, partial, asum_part);
    hipLaunchKernelGGL(kb2, dim3(16, NU), dim3(256), 0, stream,
                       asum_part, partial, centroids, out);
}